// Round 6
// baseline (480.555 us; speedup 1.0000x reference)
//
#include <hip/hip_runtime.h>
#include <hip/hip_bf16.h>
#include <stdint.h>

// ---------------------------------------------------------------------------
// VarianceAdaptor. Round 6: CK-style pipeline done right.
//   ring-3 LDS x 2-deep register prefetch: ds_write at iter kb consumes
//   global loads issued 2 iterations earlier (~900+ cyc in flight), barrier
//   needs NO vmcnt drain (plain loads -> registers). Compiler emits
//   vmcnt(6/12) automatically from register deps — the AITER pattern.
//   Mode-0 epilogue: h1b stored in thread-contiguous permuted channel order
//   (one dwordx4 per (mi,r) instead of 8 scalar shorts); wt2's K-rows are
//   permuted to match in k_prep, so conv2 is unchanged numerically.
// ---------------------------------------------------------------------------

typedef __bf16 bf16;
typedef __attribute__((ext_vector_type(8))) __bf16 bf16x8;
typedef __attribute__((ext_vector_type(4))) float f32x4;

#define TSEQ 1024

// output chunk offsets (floats)
#define O1 33554432          // pitch_pred
#define O2 33587200          // energy_pred
#define O3 33619968          // log_dur
#define O4 33652736          // duration passthrough
#define O5 33685504          // mel_len
#define O6 33685536          // mel_mask

// scratch byte offsets inside d_out (512B guard before xb)
#define XB_OFF 512
#define H1B_OFF (XB_OFF + 16777216)
#define H1B_SZ 16777216
#define WT_OFF (H1B_OFF + 3 * H1B_SZ)
#define WT_SZ 393216

// ws byte offsets
#define CUM_OFF 0
#define ADDROW_OFF 131072
#define ZEROS_OFF 262144

// ---------------------------------------------------------------------------
// Fused prep: [0,4096) cvt_x | [4096,4672) cvt_w | [4672,4800) bins+zpage |
// [4800,4832) scan.
__global__ __launch_bounds__(256) void k_prep(
    const float* __restrict__ x, bf16* __restrict__ xb,
    const float* __restrict__ w1, const float* __restrict__ w2,
    bf16* __restrict__ wt,
    const float* __restrict__ pt, const float* __restrict__ et,
    const float* __restrict__ pbins, const float* __restrict__ ebins,
    int* __restrict__ addrow, float* __restrict__ zpage,
    const int* __restrict__ dur, const int* __restrict__ maxlen,
    float* __restrict__ out, int* __restrict__ cum) {
  int bid = blockIdx.x;
  int tid = threadIdx.x;
  if (bid < 4096) {
    int t = bid * 256 + tid;
    int g = t >> 5;
    int u = t & 31;
    const float4* s = (const float4*)(x + ((size_t)g << 8) + (u << 3));
    float4 a = s[0], b = s[1];
    bf16x8 o;
    o[0] = (bf16)a.x; o[1] = (bf16)a.y; o[2] = (bf16)a.z; o[3] = (bf16)a.w;
    o[4] = (bf16)b.x; o[5] = (bf16)b.y; o[6] = (bf16)b.z; o[7] = (bf16)b.w;
    *(bf16x8*)(xb + ((size_t)g << 8) + (u << 3)) = o;
  } else if (bid < 4672) {
    int bw = bid - 4096;
    int m = bw / 96;
    int r = bw % 96;
    int f = (r & 3) * 64 + (tid & 63);
    int u = (r >> 2) * 4 + (tid >> 6);   // 16B unit along k, 0..95
    const float* W = (m < 3) ? w1 : w2;
    int i = (m < 3) ? m : m - 3;
    int dt = u >> 5;
    bf16x8 o;
    if (m < 3) {
      int c0 = (u & 31) << 3;
      const float* src = W + (((size_t)(i * 3 + dt) * 256 + c0) << 8) + f;
#pragma unroll
      for (int cc = 0; cc < 8; ++cc) o[cc] = (bf16)src[(size_t)cc << 8];
    } else {
      // conv2 K-rows permuted to match h1b's thread-contiguous store order:
      // stored c' -> original n = (c'&~127) + (c'&7)*16 + ((c'>>3)&15)
      int base = (u & 16) * 8 + (u & 15);
      const float* src = W + (((size_t)(i * 3 + dt) * 256 + base) << 8) + f;
#pragma unroll
      for (int cc = 0; cc < 8; ++cc) o[cc] = (bf16)src[(size_t)(cc * 16) << 8];
    }
    *(bf16x8*)(wt + (size_t)m * 196608 + (size_t)f * 768 + (u << 3)) = o;
  } else if (bid < 4800) {
    __shared__ float pb[255], eb[255];
    if (tid < 255) { pb[tid] = pbins[tid]; eb[tid] = ebins[tid]; }
    if (bid == 4672) zpage[tid] = 0.f;    // 1 KB zeros page
    __syncthreads();
    int g = (bid - 4672) * 256 + tid;
    float pv = pt[g], ev = et[g];
    int lo = 0, hi = 255;
    while (lo < hi) { int md = (lo + hi) >> 1; if (pb[md] < pv) lo = md + 1; else hi = md; }
    int pi = lo;
    lo = 0; hi = 255;
    while (lo < hi) { int md = (lo + hi) >> 1; if (eb[md] < ev) lo = md + 1; else hi = md; }
    addrow[g] = pi | (lo << 16);
  } else {
    __shared__ int lds[256];
    int b = bid - 4800;
    int4 d = ((const int4*)(dur + b * 1024))[tid];
    int p0 = d.x, p1 = p0 + d.y, p2 = p1 + d.z, p3 = p2 + d.w;
    int val = p3;
    lds[tid] = val;
    __syncthreads();
    for (int off = 1; off < 256; off <<= 1) {
      int t = (tid >= off) ? lds[tid - off] : 0;
      __syncthreads();
      val += t;
      lds[tid] = val;
      __syncthreads();
    }
    int excl = val - p3;
    int4 c;
    c.x = excl + p0; c.y = excl + p1; c.z = excl + p2; c.w = excl + p3;
    ((int4*)(cum + b * 1024))[tid] = c;
    float4 fd;
    fd.x = (float)d.x; fd.y = (float)d.y; fd.z = (float)d.z; fd.w = (float)d.w;
    ((float4*)(out + O4 + b * 1024))[tid] = fd;
    if (tid == 255) {
      int mel = val < maxlen[0] ? val : maxlen[0];
      out[O5 + b] = (float)mel;
    }
  }
}

// ---------------------------------------------------------------------------
// Fused conv(k=3) GEMM + bias + ReLU + LN (+ linear head for mode=1).
// grid (256, 3); 4 waves; wave (rh,ch): 64x128 tile, 4x8 MFMA 16x16x32 bf16.
__global__ __launch_bounds__(256, 2) void k_conv(
    const char* __restrict__ Ab, size_t AperY, const char* __restrict__ Wb,
    const float* __restrict__ bias0, const float* __restrict__ gamma0,
    const float* __restrict__ beta0, char* __restrict__ hout0,
    const float* __restrict__ lw0, const float* __restrict__ lb0,
    const unsigned char* __restrict__ mask, float* __restrict__ outb,
    const char* __restrict__ zpage, int mode) {
  __shared__ __align__(16) char Ls[3][24576];   // per slot: A 8KB | B 16KB
  __shared__ float redS[128][2];
  __shared__ float redS2[128][2];
  __shared__ float predr[128][2];

  const int tid = threadIdx.x;
  const int wv = tid >> 6;
  const int ln = tid & 63;
  const int q = ln >> 4;
  const int m16 = ln & 15;
  const int rh = wv >> 1;
  const int ch = wv & 1;
  const int y = blockIdx.y;
  const int g0 = blockIdx.x << 7;
  const int t0 = g0 & (TSEQ - 1);

  const char* A = Ab + (size_t)y * AperY;
  const char* W = Wb + (size_t)y * WT_SZ;

  // staging lane geometry (R3/R5-verified conflict-free LDS image)
  const int srow = ln >> 2;
  const int slot = ln & 3;
  const int usw = slot ^ ((srow >> 1) & 3);   // XOR swizzle at the ds_write
  const int rbase = wv * 16 + srow;
  const int wrO = wv * 1024 + srow * 64 + usw * 16;

  const char* srcA[2][3];
#pragma unroll
  for (int j = 0; j < 2; ++j)
#pragma unroll
    for (int dt = 0; dt < 3; ++dt) {
      int rr = j * 64 + rbase + dt - 1;
      srcA[j][dt] = ((unsigned)(t0 + rr) < 1024u)
          ? A + ((size_t)(g0 + rr) * 256 + slot * 8) * 2
          : zpage + slot * 16;
    }
  const char* bsrc[4];
#pragma unroll
  for (int j = 0; j < 4; ++j) {
    int f = j * 64 + wv * 16 + srow;
    bsrc[j] = W + ((size_t)f * 768 + slot * 8) * 2;
  }

  const int spq = (q ^ ((m16 >> 1) & 3)) << 4;
  const int aoff = (rh * 64 + m16) * 64 + spq;
  const int boff = 8192 + (ch * 128 + m16) * 64 + spq;

  f32x4 acc[4][8];
#pragma unroll
  for (int a = 0; a < 4; a++)
#pragma unroll
    for (int b = 0; b < 8; b++) acc[a][b] = (f32x4){0.f, 0.f, 0.f, 0.f};

  float4 ra[2][2], rb[2][4];   // 2-deep register prefetch

#define GLOADR(SET, KB)                                                       \
  {                                                                           \
    _Pragma("unroll") for (int j = 0; j < 2; ++j)                             \
        ra[SET][j] = *(const float4*)(srcA[j][(KB) >> 3] + ((KB) & 7) * 64);  \
    _Pragma("unroll") for (int j = 0; j < 4; ++j)                             \
        rb[SET][j] = *(const float4*)(bsrc[j] + (KB) * 64);                   \
  }
#define DSW(SLOT, SET)                                                        \
  {                                                                           \
    _Pragma("unroll") for (int j = 0; j < 2; ++j)                             \
        *(float4*)(Ls[SLOT] + j * 4096 + wrO) = ra[SET][j];                   \
    _Pragma("unroll") for (int j = 0; j < 4; ++j)                             \
        *(float4*)(Ls[SLOT] + 8192 + j * 4096 + wrO) = rb[SET][j];            \
  }

  // prologue: chunks 0,1 -> LDS slots 0,1; chunks 2,3 in registers/in flight
  GLOADR(0, 0);
  GLOADR(1, 1);
  DSW(0, 0);
  GLOADR(0, 2);
  DSW(1, 1);
  GLOADR(1, 3);
  __syncthreads();

#pragma unroll
  for (int kb = 0; kb < 24; ++kb) {
    // chunk kb+2's loads were issued 2 iterations ago -> vmcnt(6/12), no drain
    if (kb < 22) DSW((kb + 2) % 3, kb & 1);
    if (kb < 20) GLOADR(kb & 1, kb + 4);
    bf16x8 af[4], bfr[8];
#pragma unroll
    for (int mi = 0; mi < 4; ++mi)
      af[mi] = *(const bf16x8*)(Ls[kb % 3] + aoff + mi * 1024);
#pragma unroll
    for (int ni = 0; ni < 8; ++ni)
      bfr[ni] = *(const bf16x8*)(Ls[kb % 3] + boff + ni * 1024);
#pragma unroll
    for (int mi = 0; mi < 4; ++mi)
#pragma unroll
      for (int ni = 0; ni < 8; ++ni)
        acc[mi][ni] = __builtin_amdgcn_mfma_f32_16x16x32_bf16(
            af[mi], bfr[ni], acc[mi][ni], 0, 0, 0);
    __syncthreads();
  }
#undef GLOADR
#undef DSW

  // bias + ReLU + LN stats
  const float* bias = bias0 + y * 256;
  const float* gamma = gamma0 + y * 256;
  const float* beta = beta0 + y * 256;
  float bias_v[8], g_v[8], be_v[8], lw_v[8];
#pragma unroll
  for (int ni = 0; ni < 8; ni++) {
    int nf = (ch << 7) + (ni << 4) + m16;
    bias_v[ni] = bias[nf];
    g_v[ni] = gamma[nf];
    be_v[ni] = beta[nf];
  }
  if (mode) {
    const float* lw = lw0 + y * 256;
#pragma unroll
    for (int ni = 0; ni < 8; ni++) lw_v[ni] = lw[(ch << 7) + (ni << 4) + m16];
  }

#pragma unroll
  for (int mi = 0; mi < 4; mi++) {
#pragma unroll
    for (int r = 0; r < 4; r++) {
      float s1 = 0.f, s2 = 0.f;
#pragma unroll
      for (int ni = 0; ni < 8; ni++) {
        float v = acc[mi][ni][r] + bias_v[ni];
        v = fmaxf(v, 0.f);
        acc[mi][ni][r] = v;
        s1 += v;
        s2 += v * v;
      }
#pragma unroll
      for (int d = 1; d < 16; d <<= 1) {
        s1 += __shfl_xor(s1, d);
        s2 += __shfl_xor(s2, d);
      }
      if (m16 == 0) {
        int m = (rh << 6) + (mi << 4) + (q << 2) + r;
        redS[m][ch] = s1;
        redS2[m][ch] = s2;
      }
    }
  }
  __syncthreads();

  if (mode == 0) {
    // h1b stored in permuted channel order: stored c' = ch*128 + m16*8 + ni
    // (original n = ch*128 + ni*16 + m16). wt2's K-rows match (k_prep).
    bf16* hp = (bf16*)(hout0 + (size_t)y * H1B_SZ);
#pragma unroll
    for (int mi = 0; mi < 4; mi++) {
#pragma unroll
      for (int r = 0; r < 4; r++) {
        int m = (rh << 6) + (mi << 4) + (q << 2) + r;
        float mu = (redS[m][0] + redS[m][1]) * 0.00390625f;
        float var = (redS2[m][0] + redS2[m][1]) * 0.00390625f - mu * mu;
        float rs = rsqrtf(var + 1e-5f);
        int gg = g0 + m;
        bf16x8 o;
#pragma unroll
        for (int ni = 0; ni < 8; ni++)
          o[ni] = (bf16)((acc[mi][ni][r] - mu) * rs * g_v[ni] + be_v[ni]);
        *(bf16x8*)(hp + ((size_t)gg << 8) + (ch << 7) + (m16 << 3)) = o;
      }
    }
  } else {
#pragma unroll
    for (int mi = 0; mi < 4; mi++) {
#pragma unroll
      for (int r = 0; r < 4; r++) {
        int m = (rh << 6) + (mi << 4) + (q << 2) + r;
        float mu = (redS[m][0] + redS[m][1]) * 0.00390625f;
        float var = (redS2[m][0] + redS2[m][1]) * 0.00390625f - mu * mu;
        float rs = rsqrtf(var + 1e-5f);
        float p = 0.f;
#pragma unroll
        for (int ni = 0; ni < 8; ni++) {
          float v = (acc[mi][ni][r] - mu) * rs * g_v[ni] + be_v[ni];
          p += v * lw_v[ni];
        }
#pragma unroll
        for (int d = 1; d < 16; d <<= 1) p += __shfl_xor(p, d);
        if (m16 == 0) predr[m][ch] = p;
      }
    }
    __syncthreads();
    if (tid < 128) {
      int gg = g0 + tid;
      float p = predr[tid][0] + predr[tid][1] + lb0[y];
      if (mask[gg]) p = 0.f;
      float* pd = outb + (y == 0 ? O3 : (y == 1 ? O1 : O2));
      pd[gg] = p;
    }
  }
}

// ---------------------------------------------------------------------------
// Length regulation. 16 rows/block, grid 8192 (covers all B*M = 131072 rows).
__global__ __launch_bounds__(256) void k_lr(const float* __restrict__ x,
                                            const int* __restrict__ cum,
                                            const int* __restrict__ addrow,
                                            const float* __restrict__ pemb,
                                            const float* __restrict__ eemb,
                                            const int* __restrict__ maxlen,
                                            float* __restrict__ outb) {
  __shared__ int cl[1024];
  int tid = threadIdx.x;
  int rid0 = blockIdx.x << 4;
  int b = rid0 >> 12;
  ((int4*)cl)[tid] = ((const int4*)(cum + (b << 10)))[tid];
  __syncthreads();
  int lane = tid & 63;
  int wv = tid >> 6;
  int total = cl[1023];
  int ml = maxlen[0];
  int mel = total < ml ? total : ml;
  int c1 = cl[lane * 16 + 15];
#pragma unroll
  for (int rr = 0; rr < 4; ++rr) {
    int rid = rid0 + (wv << 2) + rr;
    int j = rid & 4095;
    bool valid = j < mel;
    float4 res = {0.f, 0.f, 0.f, 0.f};
    if (valid) {
      unsigned long long m1 = __ballot(j < c1);
      int s = __ffsll((unsigned long long)m1) - 1;
      unsigned long long m2 = __ballot(j < cl[s * 16 + (lane & 15)]);
      int p = __ffsll((unsigned long long)m2) - 1;
      int i = s * 16 + p;
      int ar = addrow[(b << 10) + i];
      int pi = ar & 0xffff, ei = ar >> 16;
      const float4* xr = (const float4*)(x + (((size_t)(b << 10) + i) << 8));
      const float4* pr = (const float4*)(pemb + ((size_t)pi << 8));
      const float4* er = (const float4*)(eemb + ((size_t)ei << 8));
      float4 a = xr[lane], pp = pr[lane], e = er[lane];
      res.x = a.x + pp.x + e.x;
      res.y = a.y + pp.y + e.y;
      res.z = a.z + pp.z + e.z;
      res.w = a.w + pp.w + e.w;
    }
    ((float4*)(outb + ((size_t)rid << 8)))[lane] = res;
    if (lane == 0) outb[O6 + rid] = valid ? 0.f : 1.f;
  }
}

// ---------------------------------------------------------------------------
extern "C" void kernel_launch(void* const* d_in, const int* in_sizes, int n_in,
                              void* d_out, int out_size, void* d_ws, size_t ws_size,
                              hipStream_t stream) {
  const float* x = (const float*)d_in[0];
  const unsigned char* src_mask = (const unsigned char*)d_in[1];
  const int* dur = (const int*)d_in[2];
  const float* pt = (const float*)d_in[3];
  const float* et = (const float*)d_in[4];
  const int* maxlen = (const int*)d_in[5];
  const float* w1 = (const float*)d_in[6];
  const float* b1 = (const float*)d_in[7];
  const float* g1 = (const float*)d_in[8];
  const float* be1 = (const float*)d_in[9];
  const float* w2 = (const float*)d_in[10];
  const float* b2 = (const float*)d_in[11];
  const float* g2 = (const float*)d_in[12];
  const float* be2 = (const float*)d_in[13];
  const float* lw = (const float*)d_in[14];
  const float* lb = (const float*)d_in[15];
  const float* pbins = (const float*)d_in[16];
  const float* pemb = (const float*)d_in[17];
  const float* ebins = (const float*)d_in[18];
  const float* eemb = (const float*)d_in[19];

  float* outf = (float*)d_out;
  char* ob = (char*)d_out;
  bf16* xb = (bf16*)(ob + XB_OFF);
  char* h1b = ob + H1B_OFF;
  bf16* wt = (bf16*)(ob + WT_OFF);
  int* cum = (int*)((char*)d_ws + CUM_OFF);
  int* addrow = (int*)((char*)d_ws + ADDROW_OFF);
  float* zpage = (float*)((char*)d_ws + ZEROS_OFF);

  hipLaunchKernelGGL(k_prep, dim3(4832), dim3(256), 0, stream,
                     x, xb, w1, w2, wt, pt, et, pbins, ebins, addrow, zpage,
                     dur, maxlen, outf, cum);
  hipLaunchKernelGGL(k_conv, dim3(256, 3), dim3(256), 0, stream,
                     (const char*)xb, (size_t)0, (const char*)wt, b1, g1, be1,
                     h1b, lw, lb, src_mask, outf, (const char*)zpage, 0);
  hipLaunchKernelGGL(k_conv, dim3(256, 3), dim3(256), 0, stream,
                     (const char*)h1b, (size_t)H1B_SZ,
                     (const char*)(ob + WT_OFF + 3 * WT_SZ), b2, g2, be2,
                     (char*)nullptr, lw, lb, src_mask, outf,
                     (const char*)zpage, 1);
  hipLaunchKernelGGL(k_lr, dim3(8192), dim3(256), 0, stream, x, cum, addrow,
                     pemb, eemb, maxlen, outf);
}

// Round 7
// 469.967 us; speedup vs baseline: 1.0225x; 1.0225x over previous
//
#include <hip/hip_runtime.h>
#include <hip/hip_bf16.h>
#include <stdint.h>

// ---------------------------------------------------------------------------
// VarianceAdaptor. Round 7: CK pipeline with spill-free register budget.
// R5/R6 post-mortem: WRITE_SIZE 184/375 MB vs 50 MB intentional = scratch
// spills from register over-subscription (acc128+frags48+prefetch48+ptrs).
// Fix: 512-thread blocks, 8 waves of 64x64 (acc 64, frags 32, prefetch 24,
// total ~155 VGPR). Ring-3 LDS x 2-deep register prefetch kept: ds_write at
// iter kb consumes global loads issued 2 iterations (~1000 cyc) earlier;
// barrier needs no vmcnt drain (loads target registers).
// ---------------------------------------------------------------------------

typedef __bf16 bf16;
typedef __attribute__((ext_vector_type(8))) __bf16 bf16x8;
typedef __attribute__((ext_vector_type(4))) float f32x4;

#define TSEQ 1024

// output chunk offsets (floats)
#define O1 33554432          // pitch_pred
#define O2 33587200          // energy_pred
#define O3 33619968          // log_dur
#define O4 33652736          // duration passthrough
#define O5 33685504          // mel_len
#define O6 33685536          // mel_mask

// scratch byte offsets inside d_out (512B guard before xb)
#define XB_OFF 512
#define H1B_OFF (XB_OFF + 16777216)
#define H1B_SZ 16777216
#define WT_OFF (H1B_OFF + 3 * H1B_SZ)
#define WT_SZ 393216

// ws byte offsets
#define CUM_OFF 0
#define ADDROW_OFF 131072
#define ZEROS_OFF 262144

// ---------------------------------------------------------------------------
// Fused prep: [0,4096) cvt_x | [4096,4672) cvt_w | [4672,4800) bins+zpage |
// [4800,4832) scan.
__global__ __launch_bounds__(256) void k_prep(
    const float* __restrict__ x, bf16* __restrict__ xb,
    const float* __restrict__ w1, const float* __restrict__ w2,
    bf16* __restrict__ wt,
    const float* __restrict__ pt, const float* __restrict__ et,
    const float* __restrict__ pbins, const float* __restrict__ ebins,
    int* __restrict__ addrow, float* __restrict__ zpage,
    const int* __restrict__ dur, const int* __restrict__ maxlen,
    float* __restrict__ out, int* __restrict__ cum) {
  int bid = blockIdx.x;
  int tid = threadIdx.x;
  if (bid < 4096) {
    int t = bid * 256 + tid;
    int g = t >> 5;
    int u = t & 31;
    const float4* s = (const float4*)(x + ((size_t)g << 8) + (u << 3));
    float4 a = s[0], b = s[1];
    bf16x8 o;
    o[0] = (bf16)a.x; o[1] = (bf16)a.y; o[2] = (bf16)a.z; o[3] = (bf16)a.w;
    o[4] = (bf16)b.x; o[5] = (bf16)b.y; o[6] = (bf16)b.z; o[7] = (bf16)b.w;
    *(bf16x8*)(xb + ((size_t)g << 8) + (u << 3)) = o;
  } else if (bid < 4672) {
    int bw = bid - 4096;
    int m = bw / 96;
    int r = bw % 96;
    int f = (r & 3) * 64 + (tid & 63);
    int u = (r >> 2) * 4 + (tid >> 6);   // 16B unit along k, 0..95
    const float* W = (m < 3) ? w1 : w2;
    int i = (m < 3) ? m : m - 3;
    int dt = u >> 5;
    int c0 = (u & 31) << 3;
    const float* src = W + (((size_t)(i * 3 + dt) * 256 + c0) << 8) + f;
    bf16x8 o;
#pragma unroll
    for (int cc = 0; cc < 8; ++cc) o[cc] = (bf16)src[(size_t)cc << 8];
    *(bf16x8*)(wt + (size_t)m * 196608 + (size_t)f * 768 + (u << 3)) = o;
  } else if (bid < 4800) {
    __shared__ float pb[255], eb[255];
    if (tid < 255) { pb[tid] = pbins[tid]; eb[tid] = ebins[tid]; }
    if (bid == 4672) zpage[tid] = 0.f;    // 1 KB zeros page
    __syncthreads();
    int g = (bid - 4672) * 256 + tid;
    float pv = pt[g], ev = et[g];
    int lo = 0, hi = 255;
    while (lo < hi) { int md = (lo + hi) >> 1; if (pb[md] < pv) lo = md + 1; else hi = md; }
    int pi = lo;
    lo = 0; hi = 255;
    while (lo < hi) { int md = (lo + hi) >> 1; if (eb[md] < ev) lo = md + 1; else hi = md; }
    addrow[g] = pi | (lo << 16);
  } else {
    __shared__ int lds[256];
    int b = bid - 4800;
    int4 d = ((const int4*)(dur + b * 1024))[tid];
    int p0 = d.x, p1 = p0 + d.y, p2 = p1 + d.z, p3 = p2 + d.w;
    int val = p3;
    lds[tid] = val;
    __syncthreads();
    for (int off = 1; off < 256; off <<= 1) {
      int t = (tid >= off) ? lds[tid - off] : 0;
      __syncthreads();
      val += t;
      lds[tid] = val;
      __syncthreads();
    }
    int excl = val - p3;
    int4 c;
    c.x = excl + p0; c.y = excl + p1; c.z = excl + p2; c.w = excl + p3;
    ((int4*)(cum + b * 1024))[tid] = c;
    float4 fd;
    fd.x = (float)d.x; fd.y = (float)d.y; fd.z = (float)d.z; fd.w = (float)d.w;
    ((float4*)(out + O4 + b * 1024))[tid] = fd;
    if (tid == 255) {
      int mel = val < maxlen[0] ? val : maxlen[0];
      out[O5 + b] = (float)mel;
    }
  }
}

// ---------------------------------------------------------------------------
// Fused conv(k=3) GEMM + bias + ReLU + LN (+ linear head for mode=1).
// grid (256, 3); 512 threads = 8 waves; wave (rh,ch) = 64x64 tile (4x4 MFMA
// 16x16x32 bf16, acc = 64 VGPRs). Ring-3 LDS, 2-deep register prefetch.
__global__ __launch_bounds__(512, 2) void k_conv(
    const char* __restrict__ Ab, size_t AperY, const char* __restrict__ Wb,
    const float* __restrict__ bias0, const float* __restrict__ gamma0,
    const float* __restrict__ beta0, char* __restrict__ hout0,
    const float* __restrict__ lw0, const float* __restrict__ lb0,
    const unsigned char* __restrict__ mask, float* __restrict__ outb,
    const char* __restrict__ zpage, int mode) {
  __shared__ __align__(16) char Ls[3][24576];   // per slot: A 8KB | B 16KB
  __shared__ float redS[128][4];
  __shared__ float redS2[128][4];
  __shared__ float predr[128][4];

  const int tid = threadIdx.x;
  const int wv = tid >> 6;
  const int ln = tid & 63;
  const int q = ln >> 4;
  const int m16 = ln & 15;
  const int rh = wv >> 2;        // row half (64 rows)
  const int ch = wv & 3;         // col quarter (64 cols)
  const int y = blockIdx.y;
  const int g0 = blockIdx.x << 7;
  const int t0 = g0 & (TSEQ - 1);

  const char* A = Ab + (size_t)y * AperY;
  const char* W = Wb + (size_t)y * WT_SZ;

  // staging lane geometry: thread = (row ar 0..127, 16B slot 0..3)
  const int ar = tid >> 2;
  const int slot = tid & 3;
  const int usw = slot ^ ((ar >> 1) & 3);   // XOR swizzle at the ds_write
  const int wrA = ar * 64 + usw * 16;       // also B offset (f = ar [+128])

  const char* srcA[3];
#pragma unroll
  for (int dt = 0; dt < 3; ++dt) {
    int rr = ar + dt - 1;
    srcA[dt] = ((unsigned)(t0 + rr) < 1024u)
        ? A + ((size_t)(g0 + rr) * 256 + slot * 8) * 2
        : zpage + slot * 16;
  }
  const char* bsrc[2];
#pragma unroll
  for (int j = 0; j < 2; ++j)
    bsrc[j] = W + ((size_t)(ar + j * 128) * 768 + slot * 8) * 2;

  const int spq = (q ^ ((m16 >> 1) & 3)) << 4;
  const int aoff = (rh * 64 + m16) * 64 + spq;
  const int boff = 8192 + (ch * 64 + m16) * 64 + spq;

  f32x4 acc[4][4];
#pragma unroll
  for (int a = 0; a < 4; a++)
#pragma unroll
    for (int b = 0; b < 4; b++) acc[a][b] = (f32x4){0.f, 0.f, 0.f, 0.f};

  float4 ra[2], rb[2][2];   // 2-deep register prefetch (~24 VGPRs)

#define GLOADR(SET, KB)                                                       \
  {                                                                           \
    ra[SET] = *(const float4*)(srcA[(KB) >> 3] + ((KB) & 7) * 64);            \
    rb[SET][0] = *(const float4*)(bsrc[0] + (KB) * 64);                       \
    rb[SET][1] = *(const float4*)(bsrc[1] + (KB) * 64);                       \
  }
#define DSW(SL, SET)                                                          \
  {                                                                           \
    *(float4*)(Ls[SL] + wrA) = ra[SET];                                       \
    *(float4*)(Ls[SL] + 8192 + wrA) = rb[SET][0];                             \
    *(float4*)(Ls[SL] + 16384 + wrA) = rb[SET][1];                            \
  }

  // prologue: chunks 0,1 -> slots 0,1; chunks 2,3 in registers / in flight
  GLOADR(0, 0);
  GLOADR(1, 1);
  DSW(0, 0);
  GLOADR(0, 2);
  DSW(1, 1);
  GLOADR(1, 3);
  __syncthreads();

#pragma unroll
  for (int kb = 0; kb < 24; ++kb) {
    if (kb < 22) DSW((kb + 2) % 3, kb & 1);   // chunk kb+2 (loads 2 iters old)
    if (kb < 20) GLOADR(kb & 1, kb + 4);      // stays in flight over barriers
    bf16x8 af[4], bfr[4];
#pragma unroll
    for (int mi = 0; mi < 4; ++mi)
      af[mi] = *(const bf16x8*)(Ls[kb % 3] + aoff + mi * 1024);
#pragma unroll
    for (int ni = 0; ni < 4; ++ni)
      bfr[ni] = *(const bf16x8*)(Ls[kb % 3] + boff + ni * 1024);
#pragma unroll
    for (int mi = 0; mi < 4; ++mi)
#pragma unroll
      for (int ni = 0; ni < 4; ++ni)
        acc[mi][ni] = __builtin_amdgcn_mfma_f32_16x16x32_bf16(
            af[mi], bfr[ni], acc[mi][ni], 0, 0, 0);
    __syncthreads();
  }
#undef GLOADR
#undef DSW

  // bias + ReLU + LN stats (row partials per col-quarter into LDS)
  const float* bias = bias0 + y * 256;
  const float* gamma = gamma0 + y * 256;
  const float* beta = beta0 + y * 256;
  float bias_v[4], g_v[4], be_v[4], lw_v[4];
#pragma unroll
  for (int ni = 0; ni < 4; ni++) {
    int nf = (ch << 6) + (ni << 4) + m16;
    bias_v[ni] = bias[nf];
    g_v[ni] = gamma[nf];
    be_v[ni] = beta[nf];
  }
  if (mode) {
    const float* lw = lw0 + y * 256;
#pragma unroll
    for (int ni = 0; ni < 4; ni++) lw_v[ni] = lw[(ch << 6) + (ni << 4) + m16];
  }

#pragma unroll
  for (int mi = 0; mi < 4; mi++) {
#pragma unroll
    for (int r = 0; r < 4; r++) {
      float s1 = 0.f, s2 = 0.f;
#pragma unroll
      for (int ni = 0; ni < 4; ni++) {
        float v = acc[mi][ni][r] + bias_v[ni];
        v = fmaxf(v, 0.f);
        acc[mi][ni][r] = v;
        s1 += v;
        s2 += v * v;
      }
#pragma unroll
      for (int d = 1; d < 16; d <<= 1) {
        s1 += __shfl_xor(s1, d);
        s2 += __shfl_xor(s2, d);
      }
      if (m16 == 0) {
        int m = (rh << 6) + (mi << 4) + (q << 2) + r;
        redS[m][ch] = s1;
        redS2[m][ch] = s2;
      }
    }
  }
  __syncthreads();

  if (mode == 0) {
    bf16* hp = (bf16*)(hout0 + (size_t)y * H1B_SZ);
#pragma unroll
    for (int mi = 0; mi < 4; mi++) {
#pragma unroll
      for (int r = 0; r < 4; r++) {
        int m = (rh << 6) + (mi << 4) + (q << 2) + r;
        float mu = (redS[m][0] + redS[m][1] + redS[m][2] + redS[m][3]) * 0.00390625f;
        float var = (redS2[m][0] + redS2[m][1] + redS2[m][2] + redS2[m][3]) * 0.00390625f - mu * mu;
        float rs = rsqrtf(var + 1e-5f);
        int gg = g0 + m;
#pragma unroll
        for (int ni = 0; ni < 4; ni++) {
          float v = (acc[mi][ni][r] - mu) * rs * g_v[ni] + be_v[ni];
          int n = (ch << 6) + (ni << 4) + m16;
          hp[((size_t)gg << 8) + n] = (bf16)v;
        }
      }
    }
  } else {
#pragma unroll
    for (int mi = 0; mi < 4; mi++) {
#pragma unroll
      for (int r = 0; r < 4; r++) {
        int m = (rh << 6) + (mi << 4) + (q << 2) + r;
        float mu = (redS[m][0] + redS[m][1] + redS[m][2] + redS[m][3]) * 0.00390625f;
        float var = (redS2[m][0] + redS2[m][1] + redS2[m][2] + redS2[m][3]) * 0.00390625f - mu * mu;
        float rs = rsqrtf(var + 1e-5f);
        float p = 0.f;
#pragma unroll
        for (int ni = 0; ni < 4; ni++) {
          float v = (acc[mi][ni][r] - mu) * rs * g_v[ni] + be_v[ni];
          p += v * lw_v[ni];
        }
#pragma unroll
        for (int d = 1; d < 16; d <<= 1) p += __shfl_xor(p, d);
        if (m16 == 0) predr[m][ch] = p;
      }
    }
    __syncthreads();
    if (tid < 128) {
      int gg = g0 + tid;
      float p = predr[tid][0] + predr[tid][1] + predr[tid][2] + predr[tid][3] +
                lb0[y];
      if (mask[gg]) p = 0.f;
      float* pd = outb + (y == 0 ? O3 : (y == 1 ? O1 : O2));
      pd[gg] = p;
    }
  }
}

// ---------------------------------------------------------------------------
// Length regulation. 16 rows/block, grid 8192 (covers all B*M = 131072 rows).
__global__ __launch_bounds__(256) void k_lr(const float* __restrict__ x,
                                            const int* __restrict__ cum,
                                            const int* __restrict__ addrow,
                                            const float* __restrict__ pemb,
                                            const float* __restrict__ eemb,
                                            const int* __restrict__ maxlen,
                                            float* __restrict__ outb) {
  __shared__ int cl[1024];
  int tid = threadIdx.x;
  int rid0 = blockIdx.x << 4;
  int b = rid0 >> 12;
  ((int4*)cl)[tid] = ((const int4*)(cum + (b << 10)))[tid];
  __syncthreads();
  int lane = tid & 63;
  int wv = tid >> 6;
  int total = cl[1023];
  int ml = maxlen[0];
  int mel = total < ml ? total : ml;
  int c1 = cl[lane * 16 + 15];
#pragma unroll
  for (int rr = 0; rr < 4; ++rr) {
    int rid = rid0 + (wv << 2) + rr;
    int j = rid & 4095;
    bool valid = j < mel;
    float4 res = {0.f, 0.f, 0.f, 0.f};
    if (valid) {
      unsigned long long m1 = __ballot(j < c1);
      int s = __ffsll((unsigned long long)m1) - 1;
      unsigned long long m2 = __ballot(j < cl[s * 16 + (lane & 15)]);
      int p = __ffsll((unsigned long long)m2) - 1;
      int i = s * 16 + p;
      int ar = addrow[(b << 10) + i];
      int pi = ar & 0xffff, ei = ar >> 16;
      const float4* xr = (const float4*)(x + (((size_t)(b << 10) + i) << 8));
      const float4* pr = (const float4*)(pemb + ((size_t)pi << 8));
      const float4* er = (const float4*)(eemb + ((size_t)ei << 8));
      float4 a = xr[lane], pp = pr[lane], e = er[lane];
      res.x = a.x + pp.x + e.x;
      res.y = a.y + pp.y + e.y;
      res.z = a.z + pp.z + e.z;
      res.w = a.w + pp.w + e.w;
    }
    ((float4*)(outb + ((size_t)rid << 8)))[lane] = res;
    if (lane == 0) outb[O6 + rid] = valid ? 0.f : 1.f;
  }
}

// ---------------------------------------------------------------------------
extern "C" void kernel_launch(void* const* d_in, const int* in_sizes, int n_in,
                              void* d_out, int out_size, void* d_ws, size_t ws_size,
                              hipStream_t stream) {
  const float* x = (const float*)d_in[0];
  const unsigned char* src_mask = (const unsigned char*)d_in[1];
  const int* dur = (const int*)d_in[2];
  const float* pt = (const float*)d_in[3];
  const float* et = (const float*)d_in[4];
  const int* maxlen = (const int*)d_in[5];
  const float* w1 = (const float*)d_in[6];
  const float* b1 = (const float*)d_in[7];
  const float* g1 = (const float*)d_in[8];
  const float* be1 = (const float*)d_in[9];
  const float* w2 = (const float*)d_in[10];
  const float* b2 = (const float*)d_in[11];
  const float* g2 = (const float*)d_in[12];
  const float* be2 = (const float*)d_in[13];
  const float* lw = (const float*)d_in[14];
  const float* lb = (const float*)d_in[15];
  const float* pbins = (const float*)d_in[16];
  const float* pemb = (const float*)d_in[17];
  const float* ebins = (const float*)d_in[18];
  const float* eemb = (const float*)d_in[19];

  float* outf = (float*)d_out;
  char* ob = (char*)d_out;
  bf16* xb = (bf16*)(ob + XB_OFF);
  char* h1b = ob + H1B_OFF;
  bf16* wt = (bf16*)(ob + WT_OFF);
  int* cum = (int*)((char*)d_ws + CUM_OFF);
  int* addrow = (int*)((char*)d_ws + ADDROW_OFF);
  float* zpage = (float*)((char*)d_ws + ZEROS_OFF);

  hipLaunchKernelGGL(k_prep, dim3(4832), dim3(256), 0, stream,
                     x, xb, w1, w2, wt, pt, et, pbins, ebins, addrow, zpage,
                     dur, maxlen, outf, cum);
  hipLaunchKernelGGL(k_conv, dim3(256, 3), dim3(512), 0, stream,
                     (const char*)xb, (size_t)0, (const char*)wt, b1, g1, be1,
                     h1b, lw, lb, src_mask, outf, (const char*)zpage, 0);
  hipLaunchKernelGGL(k_conv, dim3(256, 3), dim3(512), 0, stream,
                     (const char*)h1b, (size_t)H1B_SZ,
                     (const char*)(ob + WT_OFF + 3 * WT_SZ), b2, g2, be2,
                     (char*)nullptr, lw, lb, src_mask, outf,
                     (const char*)zpage, 1);
  hipLaunchKernelGGL(k_lr, dim3(8192), dim3(256), 0, stream, x, cum, addrow,
                     pemb, eemb, maxlen, outf);
}